// Round 4
// baseline (553.367 us; speedup 1.0000x reference)
//
#include <hip/hip_runtime.h>
#include <math.h>

#define NB    64
#define DIM   256
#define TWOD  512
#define CNTE  1000
#define E2S   264          // bf16 row stride in LDS, 528 B (16B-aligned)
#define NQ    1000

typedef __attribute__((ext_vector_type(8))) short short8;
typedef __attribute__((ext_vector_type(4))) float f32x4;

union U16x8 { uint4 u; short8 s; };

__device__ __forceinline__ unsigned short f2bf(float x) {
    unsigned int u = __float_as_uint(x);
    u += 0x7fffu + ((u >> 16) & 1u);          // round-to-nearest-even
    return (unsigned short)(u >> 16);
}
__device__ __forceinline__ float bf2f(unsigned short h) {
    return __uint_as_float(((unsigned int)h) << 16);
}

// ---- precompute 1: zpre[q][o] = attn_b[o] + sum_{k<256} zq_w[q][k]*attn_W[o][k]
__global__ __launch_bounds__(128) void zpre_kernel(
    const float* __restrict__ zq_w, const float* __restrict__ attn_W,
    const float* __restrict__ attn_b, float* __restrict__ zpre)
{
    __shared__ float zq[8][DIM];
    const int t  = threadIdx.x;                    // 0..127
    const int q0 = blockIdx.x * 8;                 // 125 * 8 = 1000 rows
    const int o  = blockIdx.y * 128 + t;
    #pragma unroll
    for (int r = 0; r < 8; ++r) {
        zq[r][t]       = zq_w[(size_t)(q0 + r) * DIM + t];
        zq[r][t + 128] = zq_w[(size_t)(q0 + r) * DIM + t + 128];
    }
    __syncthreads();
    const float4* wrow = (const float4*)(attn_W + (size_t)o * TWOD);
    float acc[8];
    #pragma unroll
    for (int r = 0; r < 8; ++r) acc[r] = 0.f;
    #pragma unroll 8
    for (int kk = 0; kk < 64; ++kk) {
        float4 w = wrow[kk];
        #pragma unroll
        for (int r = 0; r < 8; ++r)
            acc[r] += w.x * zq[r][kk * 4 + 0] + w.y * zq[r][kk * 4 + 1]
                    + w.z * zq[r][kk * 4 + 2] + w.w * zq[r][kk * 4 + 3];
    }
    const float bo = attn_b[o];
    #pragma unroll
    for (int r = 0; r < 8; ++r)
        zpre[(size_t)(q0 + r) * TWOD + o] = acc[r] + bo;
}

// ---- precompute 2: e-half of attn_W (512x256) -> bf16 MFMA B-frag order ----
__global__ __launch_bounds__(256) void pack_w_kernel(
    const float* __restrict__ attn_W, unsigned short* __restrict__ wbf)
{
    int f = blockIdx.x * 256 + threadIdx.x;       // 0..131071
    int j    = f & 7;
    int lane = (f >> 3) & 63;
    int kt   = (f >> 9) & 7;
    int ot   = f >> 12;                           // 0..31
    int o  = ot * 16 + (lane & 15);
    int ke = kt * 32 + (lane >> 4) * 8 + j;
    wbf[f] = f2bf(attn_W[(size_t)o * TWOD + 256 + ke]);
}

// ---- K1: TransH projection, streaming (fission path) ----
// 8 thr/neighbor, no LDS/barriers; grid = 2B blocks of 256 (32 neighbors each).
__global__ __launch_bounds__(256) void transh_kernel(
    const int*   __restrict__ nei_rid,   // [B,64]
    const float* __restrict__ nei_e,     // [B,64,256]
    const float* __restrict__ w_r,       // [1001,256]
    unsigned short* __restrict__ etr)    // [B,64,256] bf16 out
{
    const int t    = threadIdx.x;
    const int b    = blockIdx.x >> 1;
    const int n    = (blockIdx.x & 1) * 32 + (t >> 3);
    const int q    = t & 7;
    const size_t row = (size_t)b * NB + n;
    const int rid  = nei_rid[row];
    const float4* e4 = (const float4*)(nei_e + row * DIM) + q * 8;
    const float4* w4 = (const float4*)(w_r + (size_t)rid * DIM) + q * 8;
    float4 ev[8], wv[8];
    float sew = 0.f, sww = 0.f;
    #pragma unroll
    for (int j = 0; j < 8; ++j) {
        ev[j] = e4[j]; wv[j] = w4[j];
        sew += ev[j].x * wv[j].x + ev[j].y * wv[j].y + ev[j].z * wv[j].z + ev[j].w * wv[j].w;
        sww += wv[j].x * wv[j].x + wv[j].y * wv[j].y + wv[j].z * wv[j].z + wv[j].w * wv[j].w;
    }
    sew += __shfl_xor(sew, 1); sew += __shfl_xor(sew, 2); sew += __shfl_xor(sew, 4);
    sww += __shfl_xor(sww, 1); sww += __shfl_xor(sww, 2); sww += __shfl_xor(sww, 4);
    float nc   = fmaxf(sqrtf(sww), 1e-12f);
    float coef = sew / (nc * nc);
    float maskf = (rid < CNTE) ? 1.f : 0.f;
    uint4* orow = (uint4*)(etr + row * DIM) + q * 4;
    #pragma unroll
    for (int jj = 0; jj < 4; ++jj) {
        float4 e0 = ev[jj * 2],     w0 = wv[jj * 2];
        float4 e1 = ev[jj * 2 + 1], w1 = wv[jj * 2 + 1];
        uint4 pk;
        pk.x = (unsigned int)f2bf((e0.x - coef * w0.x) * maskf)
             | ((unsigned int)f2bf((e0.y - coef * w0.y) * maskf) << 16);
        pk.y = (unsigned int)f2bf((e0.z - coef * w0.z) * maskf)
             | ((unsigned int)f2bf((e0.w - coef * w0.w) * maskf) << 16);
        pk.z = (unsigned int)f2bf((e1.x - coef * w1.x) * maskf)
             | ((unsigned int)f2bf((e1.y - coef * w1.y) * maskf) << 16);
        pk.w = (unsigned int)f2bf((e1.z - coef * w1.z) * maskf)
             | ((unsigned int)f2bf((e1.w - coef * w1.w) * maskf) << 16);
        orow[jj] = pk;
    }
}

// ---- K2: GEMM + softmax + weighted sum (fission path) ----
__global__ __launch_bounds__(256, 2) void encoder_gemm_kernel(
    const int*   __restrict__ nei_rid,   // [B,64]   (pen only)
    const float* __restrict__ nei_rw,    // [B,64]
    const int*   __restrict__ q_rid,     // [B]
    const float* __restrict__ u_a_w,     // [512]
    const float* __restrict__ zpre,      // [1000,512]
    const unsigned short* __restrict__ wbf,
    const unsigned short* __restrict__ etr,   // [B,64,256] bf16
    float*       __restrict__ out)       // [B,256]
{
    __shared__ __align__(16) unsigned short e2[NB * E2S];
    __shared__ float2 zu[TWOD];
    __shared__ __align__(16) float red_a[256];
    __shared__ float  pen[NB];
    __shared__ float  attn_lds[NB];

    const int b = blockIdx.x;
    const int t = threadIdx.x;
    const int qr = q_rid[b];

    zu[t]       = make_float2(zpre[(size_t)qr * TWOD + t],       u_a_w[t]);
    zu[t + 256] = make_float2(zpre[(size_t)qr * TWOD + t + 256], u_a_w[t + 256]);
    if (t < NB) pen[t] = (nei_rid[b * NB + t] == CNTE) ? 1e19f : 0.f;

    // stage e_tr (33 KB) into padded LDS: 2048 uint4, coalesced
    {
        const uint4* src = (const uint4*)(etr + (size_t)b * NB * DIM);
        #pragma unroll
        for (int i = 0; i < 8; ++i) {
            int idx = t + i * 256;
            int row = idx >> 5, col = idx & 31;
            *(uint4*)(e2 + row * E2S + col * 8) = src[idx];
        }
    }
    __syncthreads();

    // ---- MFMA GEMM (K=256, e-half), ot-outer, B double-buffered ----
    const int wv_id = t >> 6;
    const int lane  = t & 63;
    const int l15 = lane & 15, lq = lane >> 4;

    short8 afrag[4][8];
    #pragma unroll
    for (int mt = 0; mt < 4; ++mt)
        #pragma unroll
        for (int kt = 0; kt < 8; ++kt) {
            U16x8 u; u.u = *(const uint4*)(e2 + (mt * 16 + l15) * E2S + kt * 32 + lq * 8);
            afrag[mt][kt] = u.s;
        }

    f32x4 lpv[4];
    #pragma unroll
    for (int mt = 0; mt < 4; ++mt) lpv[mt] = (f32x4){0.f, 0.f, 0.f, 0.f};

    const uint4* wbase = (const uint4*)wbf + (size_t)(wv_id * 8) * 512 + lane;

    uint4 bufA[8], bufB[8];
    #pragma unroll
    for (int kt = 0; kt < 8; ++kt) bufA[kt] = wbase[kt * 64];

#define PROC_OT(OT, CUR, NXT, NOT)                                              \
    {                                                                           \
        _Pragma("unroll")                                                       \
        for (int kt = 0; kt < 8; ++kt) NXT[kt] = wbase[(NOT) * 512 + kt * 64];  \
        const int otg = wv_id * 8 + (OT);                                       \
        const float2 zub = zu[otg * 16 + l15];                                  \
        f32x4 acc[4];                                                           \
        _Pragma("unroll")                                                       \
        for (int mt = 0; mt < 4; ++mt)                                          \
            acc[mt] = (f32x4){zub.x, zub.x, zub.x, zub.x};                      \
        _Pragma("unroll")                                                       \
        for (int kt = 0; kt < 8; ++kt) {                                        \
            U16x8 u; u.u = CUR[kt];                                             \
            _Pragma("unroll")                                                   \
            for (int mt = 0; mt < 4; ++mt)                                      \
                acc[mt] = __builtin_amdgcn_mfma_f32_16x16x32_bf16(              \
                              afrag[mt][kt], u.s, acc[mt], 0, 0, 0);            \
        }                                                                       \
        const float uy2 = -2.0f * zub.y;                                        \
        _Pragma("unroll")                                                       \
        for (int mt = 0; mt < 4; ++mt)                                          \
            _Pragma("unroll")                                                   \
            for (int r = 0; r < 4; ++r) {                                       \
                float x = acc[mt][r];                                           \
                float e = __expf(x + x);                                        \
                lpv[mt][r] += uy2 * __builtin_amdgcn_rcpf(e + 1.0f);            \
            }                                                                   \
    }

    #pragma unroll 1
    for (int i = 0; i < 4; ++i) {
        PROC_OT(2 * i,     bufA, bufB, 2 * i + 1)
        PROC_OT(2 * i + 1, bufB, bufA, (2 * i + 2) & 7)
    }
#undef PROC_OT

    #pragma unroll
    for (int mt = 0; mt < 4; ++mt)
        #pragma unroll
        for (int r = 0; r < 4; ++r) {
            float v = lpv[mt][r];
            v += __shfl_xor(v, 1); v += __shfl_xor(v, 2);
            v += __shfl_xor(v, 4); v += __shfl_xor(v, 8);
            if (l15 == 0) red_a[wv_id * 64 + mt * 16 + lq * 4 + r] = v;
        }
    __syncthreads();

    if (t < NB) {
        float lgt = red_a[t] + red_a[64 + t] + red_a[128 + t] + red_a[192 + t]
                  - pen[t];
        float m = lgt;
        #pragma unroll
        for (int off = 32; off > 0; off >>= 1) m = fmaxf(m, __shfl_xor(m, off));
        float ex = __expf(lgt - m);
        float s = ex;
        #pragma unroll
        for (int off = 32; off > 0; off >>= 1) s += __shfl_xor(s, off);
        attn_lds[t] = ex / s + nei_rw[b * NB + t];
    }
    __syncthreads();

    float oacc = 0.f;
    #pragma unroll 8
    for (int nn = 0; nn < NB; ++nn)
        oacc += attn_lds[nn] * bf2f(e2[nn * E2S + t]);
    out[(size_t)b * DIM + t] = oacc;
}

// ---- fallback: round-3 fused kernel (proven), used when ws is small ----
__global__ __launch_bounds__(256, 2) void encoder_attn_kernel(
    const int*   __restrict__ nei_rid,
    const float* __restrict__ nei_e,
    const float* __restrict__ nei_rw,
    const int*   __restrict__ q_rid,
    const float* __restrict__ w_r,
    const float* __restrict__ zq_w,
    const float* __restrict__ attn_W,
    const float* __restrict__ attn_b,
    const float* __restrict__ u_a_w,
    const float* __restrict__ zpre,
    const unsigned short* __restrict__ wbf,
    float*       __restrict__ out,
    int has_zpre)
{
    __shared__ __align__(16) unsigned short e2[NB * E2S];
    __shared__ float2 zu[TWOD];
    __shared__ __align__(16) float red_a[256];
    __shared__ float  pen[NB];
    __shared__ float  attn_lds[NB];

    const int b = blockIdx.x;
    const int t = threadIdx.x;
    const int qr = q_rid[b];

    if (has_zpre) {
        zu[t]       = make_float2(zpre[(size_t)qr * TWOD + t],       u_a_w[t]);
        zu[t + 256] = make_float2(zpre[(size_t)qr * TWOD + t + 256], u_a_w[t + 256]);
    } else {
        red_a[t] = zq_w[(size_t)qr * DIM + t];
        __syncthreads();
        float a0 = 0.f, a1 = 0.f;
        const float4* w0 = (const float4*)(attn_W + (size_t)t * TWOD);
        const float4* w1 = (const float4*)(attn_W + (size_t)(t + 256) * TWOD);
        const float4* zz = (const float4*)red_a;
        #pragma unroll 8
        for (int kk = 0; kk < 64; ++kk) {
            float4 z = zz[kk], u0 = w0[kk], u1 = w1[kk];
            a0 += u0.x * z.x + u0.y * z.y + u0.z * z.z + u0.w * z.w;
            a1 += u1.x * z.x + u1.y * z.y + u1.z * z.z + u1.w * z.w;
        }
        zu[t]       = make_float2(a0 + attn_b[t],       u_a_w[t]);
        zu[t + 256] = make_float2(a1 + attn_b[t + 256], u_a_w[t + 256]);
        __syncthreads();
    }

    {
        const int n = t >> 2, q = t & 3;
        const int rid = nei_rid[b * NB + n];
        const float4* e4 = (const float4*)(nei_e + ((size_t)(b * NB + n)) * DIM) + q * 16;
        const float4* w4 = (const float4*)(w_r + (size_t)rid * DIM) + q * 16;
        float4 ev[16], wv[16];
        float sew = 0.f, sww = 0.f;
        #pragma unroll
        for (int j = 0; j < 16; ++j) {
            ev[j] = e4[j]; wv[j] = w4[j];
            sew += ev[j].x * wv[j].x + ev[j].y * wv[j].y + ev[j].z * wv[j].z + ev[j].w * wv[j].w;
            sww += wv[j].x * wv[j].x + wv[j].y * wv[j].y + wv[j].z * wv[j].z + wv[j].w * wv[j].w;
        }
        sew += __shfl_xor(sew, 1); sew += __shfl_xor(sew, 2);
        sww += __shfl_xor(sww, 1); sww += __shfl_xor(sww, 2);
        float nc   = fmaxf(sqrtf(sww), 1e-12f);
        float coef = sew / (nc * nc);
        float maskf = (rid < CNTE) ? 1.f : 0.f;
        if (q == 0) pen[n] = (rid == CNTE) ? 1e19f : 0.f;
        unsigned short* e2row = e2 + n * E2S + q * 64;
        #pragma unroll
        for (int jj = 0; jj < 8; ++jj) {
            float4 e0 = ev[jj * 2],     w0 = wv[jj * 2];
            float4 e1 = ev[jj * 2 + 1], w1 = wv[jj * 2 + 1];
            uint4 pk;
            pk.x = (unsigned int)f2bf((e0.x - coef * w0.x) * maskf)
                 | ((unsigned int)f2bf((e0.y - coef * w0.y) * maskf) << 16);
            pk.y = (unsigned int)f2bf((e0.z - coef * w0.z) * maskf)
                 | ((unsigned int)f2bf((e0.w - coef * w0.w) * maskf) << 16);
            pk.z = (unsigned int)f2bf((e1.x - coef * w1.x) * maskf)
                 | ((unsigned int)f2bf((e1.y - coef * w1.y) * maskf) << 16);
            pk.w = (unsigned int)f2bf((e1.z - coef * w1.z) * maskf)
                 | ((unsigned int)f2bf((e1.w - coef * w1.w) * maskf) << 16);
            *(uint4*)(e2row + jj * 8) = pk;
        }
    }
    __syncthreads();

    const int wv_id = t >> 6;
    const int lane  = t & 63;
    const int l15 = lane & 15, lq = lane >> 4;

    short8 afrag[4][8];
    #pragma unroll
    for (int mt = 0; mt < 4; ++mt)
        #pragma unroll
        for (int kt = 0; kt < 8; ++kt) {
            U16x8 u; u.u = *(const uint4*)(e2 + (mt * 16 + l15) * E2S + kt * 32 + lq * 8);
            afrag[mt][kt] = u.s;
        }

    f32x4 lpv[4];
    #pragma unroll
    for (int mt = 0; mt < 4; ++mt) lpv[mt] = (f32x4){0.f, 0.f, 0.f, 0.f};

    const uint4* wbase = (const uint4*)wbf + (size_t)(wv_id * 8) * 512 + lane;

    uint4 bufA[8], bufB[8];
    #pragma unroll
    for (int kt = 0; kt < 8; ++kt) bufA[kt] = wbase[kt * 64];

#define PROC_OT(OT, CUR, NXT, NOT)                                              \
    {                                                                           \
        _Pragma("unroll")                                                       \
        for (int kt = 0; kt < 8; ++kt) NXT[kt] = wbase[(NOT) * 512 + kt * 64];  \
        const int otg = wv_id * 8 + (OT);                                       \
        const float2 zub = zu[otg * 16 + l15];                                  \
        f32x4 acc[4];                                                           \
        _Pragma("unroll")                                                       \
        for (int mt = 0; mt < 4; ++mt)                                          \
            acc[mt] = (f32x4){zub.x, zub.x, zub.x, zub.x};                      \
        _Pragma("unroll")                                                       \
        for (int kt = 0; kt < 8; ++kt) {                                        \
            U16x8 u; u.u = CUR[kt];                                             \
            _Pragma("unroll")                                                   \
            for (int mt = 0; mt < 4; ++mt)                                      \
                acc[mt] = __builtin_amdgcn_mfma_f32_16x16x32_bf16(              \
                              afrag[mt][kt], u.s, acc[mt], 0, 0, 0);            \
        }                                                                       \
        const float uy2 = -2.0f * zub.y;                                        \
        _Pragma("unroll")                                                       \
        for (int mt = 0; mt < 4; ++mt)                                          \
            _Pragma("unroll")                                                   \
            for (int r = 0; r < 4; ++r) {                                       \
                float x = acc[mt][r];                                           \
                float e = __expf(x + x);                                        \
                lpv[mt][r] += uy2 * __builtin_amdgcn_rcpf(e + 1.0f);            \
            }                                                                   \
    }

    #pragma unroll 1
    for (int i = 0; i < 4; ++i) {
        PROC_OT(2 * i,     bufA, bufB, 2 * i + 1)
        PROC_OT(2 * i + 1, bufB, bufA, (2 * i + 2) & 7)
    }
#undef PROC_OT

    #pragma unroll
    for (int mt = 0; mt < 4; ++mt)
        #pragma unroll
        for (int r = 0; r < 4; ++r) {
            float v = lpv[mt][r];
            v += __shfl_xor(v, 1); v += __shfl_xor(v, 2);
            v += __shfl_xor(v, 4); v += __shfl_xor(v, 8);
            if (l15 == 0) red_a[wv_id * 64 + mt * 16 + lq * 4 + r] = v;
        }
    __syncthreads();

    if (t < NB) {
        float lgt = red_a[t] + red_a[64 + t] + red_a[128 + t] + red_a[192 + t]
                  - pen[t];
        float m = lgt;
        #pragma unroll
        for (int off = 32; off > 0; off >>= 1) m = fmaxf(m, __shfl_xor(m, off));
        float ex = __expf(lgt - m);
        float s = ex;
        #pragma unroll
        for (int off = 32; off > 0; off >>= 1) s += __shfl_xor(s, off);
        attn_lds[t] = ex / s + nei_rw[b * NB + t];
    }
    __syncthreads();

    float oacc = 0.f;
    #pragma unroll 8
    for (int nn = 0; nn < NB; ++nn)
        oacc += attn_lds[nn] * bf2f(e2[nn * E2S + t]);
    out[(size_t)b * DIM + t] = oacc;
}

extern "C" void kernel_launch(void* const* d_in, const int* in_sizes, int n_in,
                              void* d_out, int out_size, void* d_ws, size_t ws_size,
                              hipStream_t stream) {
    const int*   nei_rid = (const int*)  d_in[0];
    const float* nei_e   = (const float*)d_in[1];
    const float* nei_rw  = (const float*)d_in[2];
    const int*   q_rid   = (const int*)  d_in[3];
    const float* w_r     = (const float*)d_in[4];
    const float* zq_w    = (const float*)d_in[5];
    const float* attn_W  = (const float*)d_in[6];
    const float* attn_b  = (const float*)d_in[7];
    const float* u_a_w   = (const float*)d_in[8];
    // d_in[9] = u_a_b: softmax shift-invariant, unused

    float* out = (float*)d_out;
    const int B = in_sizes[3];               // 4096

    const size_t ZPRE_BYTES = (size_t)NQ * TWOD * 4;           // 2,048,000
    const size_t WBF_BYTES  = (size_t)512 * 256 * 2;           //   262,144
    const size_t ETR_BYTES  = (size_t)B * NB * DIM * 2;        // 134,217,728

    float*          zpre = (float*)d_ws;
    unsigned short* wbf;
    unsigned short* etr = nullptr;

    int mode;                                // 2 = fission, 1 = fused+zpre, 0 = degraded
    if (ws_size >= ZPRE_BYTES + WBF_BYTES + ETR_BYTES) {
        mode = 2;
        wbf = (unsigned short*)((char*)d_ws + ZPRE_BYTES);
        etr = (unsigned short*)((char*)d_ws + ZPRE_BYTES + WBF_BYTES);
    } else if (ws_size >= ZPRE_BYTES + WBF_BYTES) {
        mode = 1;
        wbf = (unsigned short*)((char*)d_ws + ZPRE_BYTES);
    } else {
        mode = 0;
        wbf = (unsigned short*)d_ws;         // proven-safe 512 KB footprint
    }

    if (mode >= 1)
        hipLaunchKernelGGL(zpre_kernel, dim3(NQ / 8, 4), dim3(128), 0, stream,
                           zq_w, attn_W, attn_b, zpre);
    hipLaunchKernelGGL(pack_w_kernel, dim3(512), dim3(256), 0, stream, attn_W, wbf);

    if (mode == 2) {
        hipLaunchKernelGGL(transh_kernel, dim3(B * 2), dim3(256), 0, stream,
                           nei_rid, nei_e, w_r, etr);
        hipLaunchKernelGGL(encoder_gemm_kernel, dim3(B), dim3(256), 0, stream,
                           nei_rid, nei_rw, q_rid, u_a_w, zpre, wbf, etr, out);
    } else {
        hipLaunchKernelGGL(encoder_attn_kernel, dim3(B), dim3(256), 0, stream,
                           nei_rid, nei_e, nei_rw, q_rid, w_r, zq_w, attn_W, attn_b,
                           u_a_w, zpre, wbf, out, mode);
    }
}

// Round 5
// 502.431 us; speedup vs baseline: 1.1014x; 1.1014x over previous
//
#include <hip/hip_runtime.h>
#include <math.h>

#define NB    64
#define DIM   256
#define TWOD  512
#define CNTE  1000
#define E2S   264          // bf16 row stride in LDS, 528 B (16B-aligned, conflict-spread)
#define NQ    1000

typedef __attribute__((ext_vector_type(8))) short short8;
typedef __attribute__((ext_vector_type(4))) float f32x4;

union U16x8 { uint4 u; short8 s; };

__device__ __forceinline__ unsigned short f2bf(float x) {
    unsigned int u = __float_as_uint(x);
    u += 0x7fffu + ((u >> 16) & 1u);          // round-to-nearest-even
    return (unsigned short)(u >> 16);
}
__device__ __forceinline__ float bf2f(unsigned short h) {
    return __uint_as_float(((unsigned int)h) << 16);
}

// ---- precompute 1: zpre[q][o] = attn_b[o] + sum_{k<256} zq_w[q][k]*attn_W[o][k]
__global__ __launch_bounds__(128) void zpre_kernel(
    const float* __restrict__ zq_w, const float* __restrict__ attn_W,
    const float* __restrict__ attn_b, float* __restrict__ zpre)
{
    __shared__ float zq[8][DIM];
    const int t  = threadIdx.x;                    // 0..127
    const int q0 = blockIdx.x * 8;                 // 125 * 8 = 1000 rows
    const int o  = blockIdx.y * 128 + t;
    #pragma unroll
    for (int r = 0; r < 8; ++r) {
        zq[r][t]       = zq_w[(size_t)(q0 + r) * DIM + t];
        zq[r][t + 128] = zq_w[(size_t)(q0 + r) * DIM + t + 128];
    }
    __syncthreads();
    const float4* wrow = (const float4*)(attn_W + (size_t)o * TWOD);
    float acc[8];
    #pragma unroll
    for (int r = 0; r < 8; ++r) acc[r] = 0.f;
    #pragma unroll 8
    for (int kk = 0; kk < 64; ++kk) {
        float4 w = wrow[kk];
        #pragma unroll
        for (int r = 0; r < 8; ++r)
            acc[r] += w.x * zq[r][kk * 4 + 0] + w.y * zq[r][kk * 4 + 1]
                    + w.z * zq[r][kk * 4 + 2] + w.w * zq[r][kk * 4 + 3];
    }
    const float bo = attn_b[o];
    #pragma unroll
    for (int r = 0; r < 8; ++r)
        zpre[(size_t)(q0 + r) * TWOD + o] = acc[r] + bo;
}

// ---- precompute 2: e-half of attn_W (512x256) -> bf16 MFMA B-frag order ----
// f = ((ot*8 + kt)*64 + lane)*8 + j ; o = ot*16+(lane&15), ke = kt*32+(lane>>4)*8+j
__global__ __launch_bounds__(256) void pack_w_kernel(
    const float* __restrict__ attn_W, unsigned short* __restrict__ wbf)
{
    int f = blockIdx.x * 256 + threadIdx.x;       // 0..131071
    int j    = f & 7;
    int lane = (f >> 3) & 63;
    int kt   = (f >> 9) & 7;
    int ot   = f >> 12;                           // 0..31
    int o  = ot * 16 + (lane & 15);
    int ke = kt * 32 + (lane >> 4) * 8 + j;
    wbf[f] = f2bf(attn_W[(size_t)o * TWOD + 256 + ke]);
}

// ---- main fused kernel: one block per batch element, 4 blocks/CU ----
__global__ __launch_bounds__(256, 4) void encoder_attn_kernel(
    const int*   __restrict__ nei_rid,   // [B,64]
    const float* __restrict__ nei_e,     // [B,64,256]
    const float* __restrict__ nei_rw,    // [B,64]
    const int*   __restrict__ q_rid,     // [B]
    const float* __restrict__ w_r,       // [1001,256]
    const float* __restrict__ zq_w,      // [1000,256]   (fallback path only)
    const float* __restrict__ attn_W,    // [512,512]    (fallback path only)
    const float* __restrict__ attn_b,    // [512]        (fallback path only)
    const float* __restrict__ u_a_w,     // [512]
    const float* __restrict__ zpre,      // [1000,512]   (z-GEMM + bias, f32)
    const unsigned short* __restrict__ wbf,   // [32][8][64][8] bf16 e-half B-frags
    float*       __restrict__ out,       // [B,256]
    int has_zpre)
{
    __shared__ __align__(16) unsigned short e2[NB * E2S];  // e_tr bf16, 33792 B
    __shared__ float2 zu[TWOD];                            // (zpre+b, u_a) 4 KB
    __shared__ __align__(16) float red_a[256];             // logit partials / zq staging
    __shared__ float  pen[NB];
    __shared__ float  attn_lds[NB];

    const int b = blockIdx.x;
    const int t = threadIdx.x;
    const int qr = q_rid[b];

    if (has_zpre) {
        zu[t]       = make_float2(zpre[(size_t)qr * TWOD + t],       u_a_w[t]);
        zu[t + 256] = make_float2(zpre[(size_t)qr * TWOD + t + 256], u_a_w[t + 256]);
    } else {
        // degraded path (small workspace): compute z-dots in-block
        red_a[t] = zq_w[(size_t)qr * DIM + t];
        __syncthreads();
        float a0 = 0.f, a1 = 0.f;
        const float4* w0 = (const float4*)(attn_W + (size_t)t * TWOD);
        const float4* w1 = (const float4*)(attn_W + (size_t)(t + 256) * TWOD);
        const float4* zz = (const float4*)red_a;
        #pragma unroll 8
        for (int kk = 0; kk < 64; ++kk) {
            float4 z = zz[kk], u0 = w0[kk], u1 = w1[kk];
            a0 += u0.x * z.x + u0.y * z.y + u0.z * z.z + u0.w * z.w;
            a1 += u1.x * z.x + u1.y * z.y + u1.z * z.z + u1.w * z.w;
        }
        zu[t]       = make_float2(a0 + attn_b[t],       u_a_w[t]);
        zu[t + 256] = make_float2(a1 + attn_b[t + 256], u_a_w[t + 256]);
        __syncthreads();
    }

    // ---- phase 1: TransH projection (8 thr/neighbor, 2 serial passes, 64 regs peak)
    {
        const int q = t & 7;
        #pragma unroll 1
        for (int half = 0; half < 2; ++half) {
            const int n = (t >> 3) + half * 32;
            const int rid = nei_rid[b * NB + n];
            const float4* e4 = (const float4*)(nei_e + ((size_t)(b * NB + n)) * DIM) + q * 8;
            const float4* w4 = (const float4*)(w_r + (size_t)rid * DIM) + q * 8;
            float4 ev[8], wv[8];
            float sew = 0.f, sww = 0.f;
            #pragma unroll
            for (int j = 0; j < 8; ++j) {
                ev[j] = e4[j]; wv[j] = w4[j];
                sew += ev[j].x * wv[j].x + ev[j].y * wv[j].y + ev[j].z * wv[j].z + ev[j].w * wv[j].w;
                sww += wv[j].x * wv[j].x + wv[j].y * wv[j].y + wv[j].z * wv[j].z + wv[j].w * wv[j].w;
            }
            sew += __shfl_xor(sew, 1); sew += __shfl_xor(sew, 2); sew += __shfl_xor(sew, 4);
            sww += __shfl_xor(sww, 1); sww += __shfl_xor(sww, 2); sww += __shfl_xor(sww, 4);
            float nc   = fmaxf(sqrtf(sww), 1e-12f);
            float coef = sew / (nc * nc);
            float maskf = (rid < CNTE) ? 1.f : 0.f;
            if (q == 0) pen[n] = (rid == CNTE) ? 1e19f : 0.f;
            unsigned short* e2row = e2 + n * E2S + q * 32;
            #pragma unroll
            for (int jj = 0; jj < 4; ++jj) {
                float4 e0 = ev[jj * 2],     w0 = wv[jj * 2];
                float4 e1 = ev[jj * 2 + 1], w1 = wv[jj * 2 + 1];
                uint4 pk;
                pk.x = (unsigned int)f2bf((e0.x - coef * w0.x) * maskf)
                     | ((unsigned int)f2bf((e0.y - coef * w0.y) * maskf) << 16);
                pk.y = (unsigned int)f2bf((e0.z - coef * w0.z) * maskf)
                     | ((unsigned int)f2bf((e0.w - coef * w0.w) * maskf) << 16);
                pk.z = (unsigned int)f2bf((e1.x - coef * w1.x) * maskf)
                     | ((unsigned int)f2bf((e1.y - coef * w1.y) * maskf) << 16);
                pk.w = (unsigned int)f2bf((e1.z - coef * w1.z) * maskf)
                     | ((unsigned int)f2bf((e1.w - coef * w1.w) * maskf) << 16);
                *(uint4*)(e2row + jj * 8) = pk;
            }
        }
    }
    __syncthreads();   // e2 + zu ready

    // ---- phase 3: MFMA GEMM (K=256, e-half), 2 M-half passes to cap regs ----
    // Per pass: af[2][8]=64 regs, batched JIT B (32 transient), acc[2]+lpv[2]=16.
    // Rows disjoint across passes -> red_a slots written once each.
    const int wv_id = t >> 6;        // wave -> o range [wv_id*128, +128)
    const int lane  = t & 63;
    const int l15 = lane & 15, lq = lane >> 4;
    const uint4* wbase = (const uint4*)wbf + (size_t)(wv_id * 8) * 512 + lane;

    #pragma unroll 1
    for (int mh = 0; mh < 2; ++mh) {
        short8 af[2][8];
        #pragma unroll
        for (int mt = 0; mt < 2; ++mt)
            #pragma unroll
            for (int kt = 0; kt < 8; ++kt) {
                U16x8 u;
                u.u = *(const uint4*)(e2 + ((mh * 2 + mt) * 16 + l15) * E2S + kt * 32 + lq * 8);
                af[mt][kt] = u.s;
            }

        f32x4 lpv[2];
        lpv[0] = (f32x4){0.f, 0.f, 0.f, 0.f};
        lpv[1] = (f32x4){0.f, 0.f, 0.f, 0.f};

        #pragma unroll 1
        for (int ot = 0; ot < 8; ++ot) {
            uint4 bb[8];
            #pragma unroll
            for (int kt = 0; kt < 8; ++kt) bb[kt] = wbase[ot * 512 + kt * 64];

            const int otg = wv_id * 8 + ot;
            const float2 zub = zu[otg * 16 + l15];
            f32x4 acc[2];
            acc[0] = (f32x4){zub.x, zub.x, zub.x, zub.x};
            acc[1] = acc[0];

            #pragma unroll
            for (int kt = 0; kt < 8; ++kt) {
                U16x8 u; u.u = bb[kt];
                acc[0] = __builtin_amdgcn_mfma_f32_16x16x32_bf16(af[0][kt], u.s, acc[0], 0, 0, 0);
                acc[1] = __builtin_amdgcn_mfma_f32_16x16x32_bf16(af[1][kt], u.s, acc[1], 0, 0, 0);
            }

            // u*tanh(x) = u - 2u*rcp(e^{2x}+1); constant u-part cancels in softmax
            const float uy2 = -2.0f * zub.y;
            #pragma unroll
            for (int mt = 0; mt < 2; ++mt)
                #pragma unroll
                for (int r = 0; r < 4; ++r) {
                    float x = acc[mt][r];
                    float e = __expf(x + x);
                    lpv[mt][r] += uy2 * __builtin_amdgcn_rcpf(e + 1.0f);
                }
        }

        // reduce over l15 (16 col-slots); rows for this pass are disjoint
        #pragma unroll
        for (int mt = 0; mt < 2; ++mt)
            #pragma unroll
            for (int r = 0; r < 4; ++r) {
                float v = lpv[mt][r];
                v += __shfl_xor(v, 1); v += __shfl_xor(v, 2);
                v += __shfl_xor(v, 4); v += __shfl_xor(v, 8);
                if (l15 == 0)
                    red_a[wv_id * 64 + (mh * 2 + mt) * 16 + lq * 4 + r] = v;
            }
    }
    __syncthreads();

    // ---- phase 4: softmax over 64 neighbors (wave 0); const terms dropped ----
    if (t < NB) {
        float lgt = red_a[t] + red_a[64 + t] + red_a[128 + t] + red_a[192 + t]
                  - pen[t];
        float m = lgt;
        #pragma unroll
        for (int off = 32; off > 0; off >>= 1) m = fmaxf(m, __shfl_xor(m, off));
        float ex = __expf(lgt - m);
        float s = ex;
        #pragma unroll
        for (int off = 32; off > 0; off >>= 1) s += __shfl_xor(s, off);
        attn_lds[t] = ex / s + nei_rw[b * NB + t];
    }
    __syncthreads();

    // ---- phase 5: out[b][k] = sum_n attn[n] * e_tr[n][k] ----
    float oacc = 0.f;
    #pragma unroll 8
    for (int nn = 0; nn < NB; ++nn)
        oacc += attn_lds[nn] * bf2f(e2[nn * E2S + t]);
    out[(size_t)b * DIM + t] = oacc;
}

extern "C" void kernel_launch(void* const* d_in, const int* in_sizes, int n_in,
                              void* d_out, int out_size, void* d_ws, size_t ws_size,
                              hipStream_t stream) {
    const int*   nei_rid = (const int*)  d_in[0];
    const float* nei_e   = (const float*)d_in[1];
    const float* nei_rw  = (const float*)d_in[2];
    const int*   q_rid   = (const int*)  d_in[3];
    const float* w_r     = (const float*)d_in[4];
    const float* zq_w    = (const float*)d_in[5];
    const float* attn_W  = (const float*)d_in[6];
    const float* attn_b  = (const float*)d_in[7];
    const float* u_a_w   = (const float*)d_in[8];
    // d_in[9] = u_a_b: softmax shift-invariant, unused

    float* out = (float*)d_out;
    const int B = in_sizes[3];               // 4096

    const size_t ZPRE_BYTES = (size_t)NQ * TWOD * 4;   // 2,048,000
    const size_t WBF_BYTES  = (size_t)512 * 256 * 2;   //   262,144
    const int has_zpre = (ws_size >= ZPRE_BYTES + WBF_BYTES) ? 1 : 0;

    float*          zpre = (float*)d_ws;
    unsigned short* wbf  = has_zpre
        ? (unsigned short*)((char*)d_ws + ZPRE_BYTES)
        : (unsigned short*)d_ws;             // proven-safe 512 KB footprint

    if (has_zpre)
        hipLaunchKernelGGL(zpre_kernel, dim3(NQ / 8, 4), dim3(128), 0, stream,
                           zq_w, attn_W, attn_b, zpre);
    hipLaunchKernelGGL(pack_w_kernel, dim3(512), dim3(256), 0, stream, attn_W, wbf);
    hipLaunchKernelGGL(encoder_attn_kernel, dim3(B), dim3(256), 0, stream,
                       nei_rid, nei_e, nei_rw, q_rid, w_r, zq_w, attn_W, attn_b,
                       u_a_w, zpre, wbf, out, has_zpre);
}

// Round 6
// 502.226 us; speedup vs baseline: 1.1018x; 1.0004x over previous
//
#include <hip/hip_runtime.h>
#include <math.h>

#define NB    64
#define DIM   256
#define TWOD  512
#define CNTE  1000
#define E2S   264          // bf16 row stride in LDS, 528 B (16B-aligned, conflict-spread)
#define NQ    1000

typedef __attribute__((ext_vector_type(8))) short short8;
typedef __attribute__((ext_vector_type(4))) float f32x4;

union U16x8 { uint4 u; short8 s; };

__device__ __forceinline__ unsigned short f2bf(float x) {
    unsigned int u = __float_as_uint(x);
    u += 0x7fffu + ((u >> 16) & 1u);          // round-to-nearest-even
    return (unsigned short)(u >> 16);
}
__device__ __forceinline__ float bf2f(unsigned short h) {
    return __uint_as_float(((unsigned int)h) << 16);
}
// packed f32x2 -> bf16x2 (RNE), low half = a. 1 inst vs ~6 for scalar path.
__device__ __forceinline__ unsigned int cvt_pk_bf16(float a, float b) {
    unsigned int r;
    asm("v_cvt_pk_bf16_f32 %0, %1, %2" : "=v"(r) : "v"(a), "v"(b));
    return r;
}

// ---- precompute 1: zpre[q][o] = attn_b[o] + sum_{k<256} zq_w[q][k]*attn_W[o][k]
__global__ __launch_bounds__(128) void zpre_kernel(
    const float* __restrict__ zq_w, const float* __restrict__ attn_W,
    const float* __restrict__ attn_b, float* __restrict__ zpre)
{
    __shared__ float zq[8][DIM];
    const int t  = threadIdx.x;                    // 0..127
    const int q0 = blockIdx.x * 8;                 // 125 * 8 = 1000 rows
    const int o  = blockIdx.y * 128 + t;
    #pragma unroll
    for (int r = 0; r < 8; ++r) {
        zq[r][t]       = zq_w[(size_t)(q0 + r) * DIM + t];
        zq[r][t + 128] = zq_w[(size_t)(q0 + r) * DIM + t + 128];
    }
    __syncthreads();
    const float4* wrow = (const float4*)(attn_W + (size_t)o * TWOD);
    float acc[8];
    #pragma unroll
    for (int r = 0; r < 8; ++r) acc[r] = 0.f;
    #pragma unroll 8
    for (int kk = 0; kk < 64; ++kk) {
        float4 w = wrow[kk];
        #pragma unroll
        for (int r = 0; r < 8; ++r)
            acc[r] += w.x * zq[r][kk * 4 + 0] + w.y * zq[r][kk * 4 + 1]
                    + w.z * zq[r][kk * 4 + 2] + w.w * zq[r][kk * 4 + 3];
    }
    const float bo = attn_b[o];
    #pragma unroll
    for (int r = 0; r < 8; ++r)
        zpre[(size_t)(q0 + r) * TWOD + o] = acc[r] + bo;
}

// ---- precompute 2: e-half of attn_W (512x256) -> bf16 MFMA B-frag order ----
// f = ((ot*8 + kt)*64 + lane)*8 + j ; o = ot*16+(lane&15), ke = kt*32+(lane>>4)*8+j
__global__ __launch_bounds__(256) void pack_w_kernel(
    const float* __restrict__ attn_W, unsigned short* __restrict__ wbf)
{
    int f = blockIdx.x * 256 + threadIdx.x;       // 0..131071
    int j    = f & 7;
    int lane = (f >> 3) & 63;
    int kt   = (f >> 9) & 7;
    int ot   = f >> 12;                           // 0..31
    int o  = ot * 16 + (lane & 15);
    int ke = kt * 32 + (lane >> 4) * 8 + j;
    wbf[f] = f2bf(attn_W[(size_t)o * TWOD + 256 + ke]);
}

// ---- main fused kernel: one block per batch element, 4 blocks/CU ----
__global__ __launch_bounds__(256, 4) void encoder_attn_kernel(
    const int*   __restrict__ nei_rid,   // [B,64]
    const float* __restrict__ nei_e,     // [B,64,256]
    const float* __restrict__ nei_rw,    // [B,64]
    const int*   __restrict__ q_rid,     // [B]
    const float* __restrict__ w_r,       // [1001,256]
    const float* __restrict__ zq_w,      // [1000,256]   (fallback path only)
    const float* __restrict__ attn_W,    // [512,512]    (fallback path only)
    const float* __restrict__ attn_b,    // [512]        (fallback path only)
    const float* __restrict__ u_a_w,     // [512]
    const float* __restrict__ zpre,      // [1000,512]   (z-GEMM + bias, f32)
    const unsigned short* __restrict__ wbf,   // [32][8][64][8] bf16 e-half B-frags
    float*       __restrict__ out,       // [B,256]
    int has_zpre)
{
    __shared__ __align__(16) unsigned short e2[NB * E2S];  // e_tr bf16, 33792 B
    __shared__ float2 zu[TWOD];                            // (zpre+b, u_a) 4 KB
    __shared__ __align__(16) float red_a[256];             // logit partials / zq staging
    __shared__ float  pen[NB];
    __shared__ float  attn_lds[NB];

    const int b = blockIdx.x;
    const int t = threadIdx.x;
    const int qr = q_rid[b];

    if (has_zpre) {
        zu[t]       = make_float2(zpre[(size_t)qr * TWOD + t],       u_a_w[t]);
        zu[t + 256] = make_float2(zpre[(size_t)qr * TWOD + t + 256], u_a_w[t + 256]);
    } else {
        // degraded path (small workspace): compute z-dots in-block
        red_a[t] = zq_w[(size_t)qr * DIM + t];
        __syncthreads();
        float a0 = 0.f, a1 = 0.f;
        const float4* w0 = (const float4*)(attn_W + (size_t)t * TWOD);
        const float4* w1 = (const float4*)(attn_W + (size_t)(t + 256) * TWOD);
        const float4* zz = (const float4*)red_a;
        #pragma unroll 8
        for (int kk = 0; kk < 64; ++kk) {
            float4 z = zz[kk], u0 = w0[kk], u1 = w1[kk];
            a0 += u0.x * z.x + u0.y * z.y + u0.z * z.z + u0.w * z.w;
            a1 += u1.x * z.x + u1.y * z.y + u1.z * z.z + u1.w * z.w;
        }
        zu[t]       = make_float2(a0 + attn_b[t],       u_a_w[t]);
        zu[t + 256] = make_float2(a1 + attn_b[t + 256], u_a_w[t + 256]);
        __syncthreads();
    }

    // ---- phase 1: TransH projection (8 thr/neighbor, 2 serial passes, 64 regs peak)
    {
        const int q  = t & 7;
        const int n0 = t >> 3;
        const int rid0 = nei_rid[b * NB + n0];        // both rids up front:
        const int rid1 = nei_rid[b * NB + n0 + 32];   // hides pass-2 gather start
        #pragma unroll 1
        for (int half = 0; half < 2; ++half) {
            const int n   = n0 + half * 32;
            const int rid = half ? rid1 : rid0;
            const float4* e4 = (const float4*)(nei_e + ((size_t)(b * NB + n)) * DIM) + q * 8;
            const float4* w4 = (const float4*)(w_r + (size_t)rid * DIM) + q * 8;
            float4 ev[8], wv[8];
            float sew = 0.f, sww = 0.f;
            #pragma unroll
            for (int j = 0; j < 8; ++j) {
                ev[j] = e4[j]; wv[j] = w4[j];
                sew += ev[j].x * wv[j].x + ev[j].y * wv[j].y + ev[j].z * wv[j].z + ev[j].w * wv[j].w;
                sww += wv[j].x * wv[j].x + wv[j].y * wv[j].y + wv[j].z * wv[j].z + wv[j].w * wv[j].w;
            }
            sew += __shfl_xor(sew, 1); sew += __shfl_xor(sew, 2); sew += __shfl_xor(sew, 4);
            sww += __shfl_xor(sww, 1); sww += __shfl_xor(sww, 2); sww += __shfl_xor(sww, 4);
            // coef = sew / max(sqrt(sww),1e-12)^2  ==  sew * rcp(max(sww,1e-24))
            const float coef = sew * __builtin_amdgcn_rcpf(fmaxf(sww, 1e-24f));
            const unsigned int mbits = (rid < CNTE) ? 0xFFFFFFFFu : 0u;  // bf16(0)=0
            if (q == 0) pen[n] = (rid == CNTE) ? 1e19f : 0.f;
            unsigned short* e2row = e2 + n * E2S + q * 32;
            #pragma unroll
            for (int jj = 0; jj < 4; ++jj) {
                float4 e0 = ev[jj * 2],     w0 = wv[jj * 2];
                float4 e1 = ev[jj * 2 + 1], w1 = wv[jj * 2 + 1];
                uint4 pk;
                pk.x = cvt_pk_bf16(fmaf(-coef, w0.x, e0.x), fmaf(-coef, w0.y, e0.y)) & mbits;
                pk.y = cvt_pk_bf16(fmaf(-coef, w0.z, e0.z), fmaf(-coef, w0.w, e0.w)) & mbits;
                pk.z = cvt_pk_bf16(fmaf(-coef, w1.x, e1.x), fmaf(-coef, w1.y, e1.y)) & mbits;
                pk.w = cvt_pk_bf16(fmaf(-coef, w1.z, e1.z), fmaf(-coef, w1.w, e1.w)) & mbits;
                *(uint4*)(e2row + jj * 8) = pk;
            }
        }
    }
    __syncthreads();   // e2 + zu ready

    // ---- phase 3: MFMA GEMM (K=256, e-half), 2 M-half passes to cap regs ----
    // B prefetched wrap-around (B is mh-independent); prefetch sits between the
    // MFMA cluster and the epilogue so the epilogue VALU/trans hides L2 latency.
    const int wv_id = t >> 6;        // wave -> o range [wv_id*128, +128)
    const int lane  = t & 63;
    const int l15 = lane & 15, lq = lane >> 4;
    const uint4* wbase = (const uint4*)wbf + (size_t)(wv_id * 8) * 512 + lane;

    uint4 bb[8];
    #pragma unroll
    for (int kt = 0; kt < 8; ++kt) bb[kt] = wbase[kt * 64];   // ot = 0

    #pragma unroll 1
    for (int mh = 0; mh < 2; ++mh) {
        short8 af[2][8];
        #pragma unroll
        for (int mt = 0; mt < 2; ++mt)
            #pragma unroll
            for (int kt = 0; kt < 8; ++kt) {
                U16x8 u;
                u.u = *(const uint4*)(e2 + ((mh * 2 + mt) * 16 + l15) * E2S + kt * 32 + lq * 8);
                af[mt][kt] = u.s;
            }

        f32x4 lpv[2];
        lpv[0] = (f32x4){0.f, 0.f, 0.f, 0.f};
        lpv[1] = (f32x4){0.f, 0.f, 0.f, 0.f};

        #pragma unroll 1
        for (int ot = 0; ot < 8; ++ot) {
            const int otg = wv_id * 8 + ot;
            const float2 zub = zu[otg * 16 + l15];
            f32x4 acc[2];
            acc[0] = (f32x4){zub.x, zub.x, zub.x, zub.x};
            acc[1] = acc[0];

            #pragma unroll
            for (int kt = 0; kt < 8; ++kt) {
                U16x8 u; u.u = bb[kt];
                acc[0] = __builtin_amdgcn_mfma_f32_16x16x32_bf16(af[0][kt], u.s, acc[0], 0, 0, 0);
                acc[1] = __builtin_amdgcn_mfma_f32_16x16x32_bf16(af[1][kt], u.s, acc[1], 0, 0, 0);
            }

            // prefetch next ot (wraps to 0 for the next mh pass; B is mh-invariant)
            #pragma unroll
            for (int kt = 0; kt < 8; ++kt)
                bb[kt] = wbase[((ot + 1) & 7) * 512 + kt * 64];

            // u*tanh(x) = u - 2u*rcp(e^{2x}+1); constant u-part cancels in softmax
            const float uy2 = -2.0f * zub.y;
            #pragma unroll
            for (int mt = 0; mt < 2; ++mt)
                #pragma unroll
                for (int r = 0; r < 4; ++r) {
                    float x = acc[mt][r];
                    float e = __expf(x + x);
                    lpv[mt][r] += uy2 * __builtin_amdgcn_rcpf(e + 1.0f);
                }
        }

        // reduce over l15 (16 col-slots); rows for this pass are disjoint
        #pragma unroll
        for (int mt = 0; mt < 2; ++mt)
            #pragma unroll
            for (int r = 0; r < 4; ++r) {
                float v = lpv[mt][r];
                v += __shfl_xor(v, 1); v += __shfl_xor(v, 2);
                v += __shfl_xor(v, 4); v += __shfl_xor(v, 8);
                if (l15 == 0)
                    red_a[wv_id * 64 + (mh * 2 + mt) * 16 + lq * 4 + r] = v;
            }
    }
    __syncthreads();

    // ---- phase 4: softmax over 64 neighbors (wave 0); const terms dropped ----
    if (t < NB) {
        float lgt = red_a[t] + red_a[64 + t] + red_a[128 + t] + red_a[192 + t]
                  - pen[t];
        float m = lgt;
        #pragma unroll
        for (int off = 32; off > 0; off >>= 1) m = fmaxf(m, __shfl_xor(m, off));
        float ex = __expf(lgt - m);
        float s = ex;
        #pragma unroll
        for (int off = 32; off > 0; off >>= 1) s += __shfl_xor(s, off);
        attn_lds[t] = ex / s + nei_rw[b * NB + t];
    }
    __syncthreads();

    // ---- phase 5: out[b][k] = sum_n attn[n] * e_tr[n][k] ----
    float oacc = 0.f;
    #pragma unroll 8
    for (int nn = 0; nn < NB; ++nn)
        oacc += attn_lds[nn] * bf2f(e2[nn * E2S + t]);
    out[(size_t)b * DIM + t] = oacc;
}

extern "C" void kernel_launch(void* const* d_in, const int* in_sizes, int n_in,
                              void* d_out, int out_size, void* d_ws, size_t ws_size,
                              hipStream_t stream) {
    const int*   nei_rid = (const int*)  d_in[0];
    const float* nei_e   = (const float*)d_in[1];
    const float* nei_rw  = (const float*)d_in[2];
    const int*   q_rid   = (const int*)  d_in[3];
    const float* w_r     = (const float*)d_in[4];
    const float* zq_w    = (const float*)d_in[5];
    const float* attn_W  = (const float*)d_in[6];
    const float* attn_b  = (const float*)d_in[7];
    const float* u_a_w   = (const float*)d_in[8];
    // d_in[9] = u_a_b: softmax shift-invariant, unused

    float* out = (float*)d_out;
    const int B = in_sizes[3];               // 4096

    const size_t ZPRE_BYTES = (size_t)NQ * TWOD * 4;   // 2,048,000
    const size_t WBF_BYTES  = (size_t)512 * 256 * 2;   //   262,144
    const int has_zpre = (ws_size >= ZPRE_BYTES + WBF_BYTES) ? 1 : 0;

    float*          zpre = (float*)d_ws;
    unsigned short* wbf  = has_zpre
        ? (unsigned short*)((char*)d_ws + ZPRE_BYTES)
        : (unsigned short*)d_ws;             // proven-safe 512 KB footprint

    if (has_zpre)
        hipLaunchKernelGGL(zpre_kernel, dim3(NQ / 8, 4), dim3(128), 0, stream,
                           zq_w, attn_W, attn_b, zpre);
    hipLaunchKernelGGL(pack_w_kernel, dim3(512), dim3(256), 0, stream, attn_W, wbf);
    hipLaunchKernelGGL(encoder_attn_kernel, dim3(B), dim3(256), 0, stream,
                       nei_rid, nei_e, nei_rw, q_rid, w_r, zq_w, attn_W, attn_b,
                       u_a_w, zpre, wbf, out, has_zpre);
}